// Round 13
// baseline (283.169 us; speedup 1.0000x reference)
//
#include <hip/hip_runtime.h>
#include <math.h>

#define B_ 2
#define S_ 2048
#define D_ 1024
#define H_ 16
#define DK_ 64
#define EPS_ 1e-5f

typedef __bf16 bf16_t;
typedef __bf16 bf16x4 __attribute__((ext_vector_type(4)));
typedef __bf16 bf16x8 __attribute__((ext_vector_type(8)));
typedef float f32x4 __attribute__((ext_vector_type(4)));
typedef unsigned long long u64;
typedef unsigned short u16;

#define MFMA16(a, b, c) __builtin_amdgcn_mfma_f32_16x16x32_bf16(a, b, c, 0, 0, 0)

__device__ __forceinline__ void gload16(const bf16_t* g, bf16_t* l) {
    __builtin_amdgcn_global_load_lds(
        (const __attribute__((address_space(1))) void*)g,
        (__attribute__((address_space(3))) void*)l, 16, 0, 0);
}

// ---------------------------------------------------------------------------
// Fused prologue: one launch, three regions (mask_pack | cvt q,k,v | cvt W*).
// ---------------------------------------------------------------------------
__global__ __launch_bounds__(256) void prep(
        const int* __restrict__ mask, u16* __restrict__ bits2,
        const float* __restrict__ q, const float* __restrict__ k,
        const float* __restrict__ v,
        bf16_t* __restrict__ xq, bf16_t* __restrict__ xk, bf16_t* __restrict__ xv,
        const float* __restrict__ Wq, const float* __restrict__ Wk,
        const float* __restrict__ Wv, const float* __restrict__ Wo,
        bf16_t* __restrict__ wq, bf16_t* __restrict__ wk,
        bf16_t* __restrict__ wv, bf16_t* __restrict__ wo)
{
    int bid = blockIdx.x;
    if (bid < 32768) {
        // mask_pack: [B,S,S] int32 -> per-(row,g) u16 streams
        size_t i = (size_t)bid * 256 + threadIdx.x;
        int m = mask[i];
        u64 wm = __ballot(m != 0);
        if ((threadIdx.x & 63) == 0) {
            size_t widx = i >> 6;
            size_t row = widx >> 5;
            int t = (int)(widx & 31);
#pragma unroll
            for (int g = 0; g < 4; ++g) {
                u16 val = 0;
#pragma unroll
                for (int tk = 0; tk < 4; ++tk)
                    val |= (u16)(((wm >> (tk * 16 + g * 4)) & 0xF) << (tk * 4));
                bits2[(row * 4 + g) * 32 + t] = val;
            }
        }
    } else if (bid < 38912) {
        int b2 = bid - 32768;                  // 6144 blocks: q,k,v (2048 each)
        int region = b2 >> 11;
        int i = ((b2 & 2047) << 8) + threadIdx.x;
        const float* in = (region == 0) ? q : (region == 1) ? k : v;
        bf16_t* out = (region == 0) ? xq : (region == 1) ? xk : xv;
        float4 v0 = reinterpret_cast<const float4*>(in)[i * 2];
        float4 v1 = reinterpret_cast<const float4*>(in)[i * 2 + 1];
        bf16x8 o = { (bf16_t)v0.x, (bf16_t)v0.y, (bf16_t)v0.z, (bf16_t)v0.w,
                     (bf16_t)v1.x, (bf16_t)v1.y, (bf16_t)v1.z, (bf16_t)v1.w };
        reinterpret_cast<bf16x8*>(out)[i] = o;
    } else {
        int b2 = bid - 38912;                  // 2048 blocks: Wq,Wk,Wv,Wo (512 each)
        int region = b2 >> 9;
        int i = ((b2 & 511) << 8) + threadIdx.x;
        const float* in = (region == 0) ? Wq : (region == 1) ? Wk : (region == 2) ? Wv : Wo;
        bf16_t* out = (region == 0) ? wq : (region == 1) ? wk : (region == 2) ? wv : wo;
        float4 v0 = reinterpret_cast<const float4*>(in)[i * 2];
        float4 v1 = reinterpret_cast<const float4*>(in)[i * 2 + 1];
        bf16x8 o = { (bf16_t)v0.x, (bf16_t)v0.y, (bf16_t)v0.z, (bf16_t)v0.w,
                     (bf16_t)v1.x, (bf16_t)v1.y, (bf16_t)v1.z, (bf16_t)v1.w };
        reinterpret_cast<bf16x8*>(out)[i] = o;
    }
}

// ---------------------------------------------------------------------------
// Shared 128x128 GEMM body (as r12).
// ---------------------------------------------------------------------------
__device__ __forceinline__ void gemm_body(
        const bf16_t* __restrict__ Asrc, const bf16_t* __restrict__ Bsrc,
        const float* __restrict__ bias, const float* __restrict__ resid,
        float* __restrict__ xout, bf16_t* __restrict__ bout,
        int mode, int m0, int n0)
{
    __shared__ bf16_t As[128 * 64];
    __shared__ bf16_t Bs[128 * 64];
    const int tid = threadIdx.x;
    const int w = tid >> 6, l = tid & 63;
    const int c = l & 15, g = l >> 4;
    const int wr = w >> 1, wc = w & 1;

    int srow[4], scol[4];
    uint32_t soff[4];
#pragma unroll
    for (int i = 0; i < 4; ++i) {
        int s = tid + i * 256;
        srow[i] = s >> 3;
        scol[i] = s & 7;
        soff[i] = (uint32_t)(s * 16) ^ (uint32_t)((srow[i] & 7) << 4);
    }

    bf16x8 areg[4], breg[4];
#pragma unroll
    for (int i = 0; i < 4; ++i) {
        areg[i] = *reinterpret_cast<const bf16x8*>(Asrc + (size_t)srow[i] * D_ + scol[i] * 8);
        breg[i] = *reinterpret_cast<const bf16x8*>(Bsrc + (size_t)srow[i] * D_ + scol[i] * 8);
    }

    f32x4 acc[4][4] = {};
    for (int kt = 0; kt < 16; ++kt) {
#pragma unroll
        for (int i = 0; i < 4; ++i) {
            *reinterpret_cast<bf16x8*>((char*)As + soff[i]) = areg[i];
            *reinterpret_cast<bf16x8*>((char*)Bs + soff[i]) = breg[i];
        }
        __syncthreads();
        if (kt + 1 < 16) {
            int k0 = (kt + 1) * 64;
#pragma unroll
            for (int i = 0; i < 4; ++i) {
                areg[i] = *reinterpret_cast<const bf16x8*>(Asrc + (size_t)srow[i] * D_ + k0 + scol[i] * 8);
                breg[i] = *reinterpret_cast<const bf16x8*>(Bsrc + (size_t)srow[i] * D_ + k0 + scol[i] * 8);
            }
        }
        bf16x8 bf0[4], bf1[4];
#pragma unroll
        for (int j = 0; j < 4; ++j) {
            int R = wc * 64 + j * 16 + c;
            const char* base = (const char*)Bs + R * 128;
            uint32_t msk = (uint32_t)((R & 7) << 4);
            bf0[j] = *reinterpret_cast<const bf16x8*>(base + ((g * 16) ^ msk));
            bf1[j] = *reinterpret_cast<const bf16x8*>(base + ((64 + g * 16) ^ msk));
        }
#pragma unroll
        for (int i = 0; i < 4; ++i) {
            int R = wr * 64 + i * 16 + c;
            const char* base = (const char*)As + R * 128;
            uint32_t msk = (uint32_t)((R & 7) << 4);
            bf16x8 a0 = *reinterpret_cast<const bf16x8*>(base + ((g * 16) ^ msk));
            bf16x8 a1 = *reinterpret_cast<const bf16x8*>(base + ((64 + g * 16) ^ msk));
#pragma unroll
            for (int j = 0; j < 4; ++j) {
                acc[i][j] = MFMA16(a0, bf0[j], acc[i][j]);
                acc[i][j] = MFMA16(a1, bf1[j], acc[i][j]);
            }
        }
        __syncthreads();
    }

#pragma unroll
    for (int i = 0; i < 4; ++i) {
#pragma unroll
        for (int j = 0; j < 4; ++j) {
#pragma unroll
            for (int r = 0; r < 4; ++r) {
                int P  = wr * 64 + i * 16 + g * 4 + r;
                int Qd = wc * 64 + j * 16 + c;
                float val = acc[i][j][r];
                if (mode == 2) {
                    int m = m0 + P, n = n0 + Qd;
                    xout[(size_t)m * D_ + n] = val + bias[n] + resid[(size_t)m * D_ + n];
                } else if (mode == 0) {
                    int m = m0 + P, n = n0 + Qd;
                    int bb = m >> 11, s = m & (S_ - 1);
                    int h = n >> 6, dk = n & 63;
                    bout[(((size_t)bb * H_ + h) * S_ + s) * DK_ + dk] = (bf16_t)(val + bias[n]);
                } else {
                    int n = n0 + P, m = m0 + Qd;
                    int bb = m >> 11, s = m & (S_ - 1);
                    int h = n >> 6, dk = n & 63;
                    bout[(((size_t)bb * H_ + h) * DK_ + dk) * S_ + s] = (bf16_t)(val + bias[n]);
                }
            }
        }
    }
}

__global__ __launch_bounds__(256) void qkv_gemm(
        const bf16_t* __restrict__ xq, const bf16_t* __restrict__ xk,
        const bf16_t* __restrict__ xv,
        const bf16_t* __restrict__ wq, const bf16_t* __restrict__ wk,
        const bf16_t* __restrict__ wv,
        const float* __restrict__ bq, const float* __restrict__ bk,
        const float* __restrict__ bv,
        bf16_t* __restrict__ qh, bf16_t* __restrict__ kh, bf16_t* __restrict__ vt)
{
    const int z = blockIdx.z;
    const int m0 = blockIdx.y * 128, n0 = blockIdx.x * 128;
    const bf16_t* X = (z == 0) ? xq : (z == 1) ? xk : xv;
    const bf16_t* W = (z == 0) ? wq : (z == 1) ? wk : wv;
    const float* bias = (z == 0) ? bq : (z == 1) ? bk : bv;
    bf16_t* out = (z == 0) ? qh : (z == 1) ? kh : vt;
    int mode = (z == 2) ? 1 : 0;
    const bf16_t* Asrc = (mode == 1) ? (W + (size_t)n0 * D_) : (X + (size_t)m0 * D_);
    const bf16_t* Bsrc = (mode == 1) ? (X + (size_t)m0 * D_) : (W + (size_t)n0 * D_);
    gemm_body(Asrc, Bsrc, bias, nullptr, nullptr, out, mode, m0, n0);
}

__global__ __launch_bounds__(256) void oproj_gemm(
        const bf16_t* __restrict__ ctx, const bf16_t* __restrict__ wo,
        const float* __restrict__ bo, const float* __restrict__ resid,
        float* __restrict__ x)
{
    const int m0 = blockIdx.y * 128, n0 = blockIdx.x * 128;
    gemm_body(ctx + (size_t)m0 * D_, wo + (size_t)n0 * D_, bo, resid, x, nullptr, 2, m0, n0);
}

// ---------------------------------------------------------------------------
// attn_stats: pass 1 only. 1024 blocks x 256 thr (4 waves x 16 q-rows = 64
// rows/block), K via 3-deep DMA (24 KB LDS), no writes except inv_l[bh*S+q].
// ---------------------------------------------------------------------------
__global__ __launch_bounds__(256) void attn_stats(
        const bf16_t* __restrict__ qh, const bf16_t* __restrict__ kh,
        const u16* __restrict__ bits2, float* __restrict__ linv)
{
    constexpr int TILE = 64;
    constexpr int NT = S_ / TILE;
    __shared__ bf16_t Kbuf[3][TILE * DK_];   // 3 x 8 KB

    const int tid = threadIdx.x;
    const int w = tid >> 6, l = tid & 63;
    const int c = l & 15, g = l >> 4;

    const int id = blockIdx.x;               // 1024 blocks
    const int xcd = id & 7, ixd = id >> 3;   // 128 per XCD = 4 bh x 32 qt
    const int bh = xcd * 4 + (ixd >> 5);
    const int qt = ixd & 31;
    const int q0 = qt * 64 + w * 16;
    const int b = bh >> 4;

    const bf16_t* Q = qh + ((size_t)bh * S_ + q0) * DK_;
    const bf16_t* K = kh + (size_t)bh * S_ * DK_;

    u64 mreg[8];
    {
        const u64* mp = reinterpret_cast<const u64*>(
            bits2 + (((size_t)b * S_ + q0 + c) * 4 + g) * 32);
#pragma unroll
        for (int i = 0; i < 8; ++i) mreg[i] = mp[i];
    }

    bf16x8 qf0 = *reinterpret_cast<const bf16x8*>(&Q[c * DK_ + g * 8]);
    bf16x8 qf1 = *reinterpret_cast<const bf16x8*>(&Q[c * DK_ + 32 + g * 8]);

    // 2 DMA slots per thread per tile: slot = w*64+l (+256)
    const int slot0 = (w << 6) + l, slot1 = slot0 + 256;
    const int r0 = slot0 >> 3, cs0 = (slot0 & 7) ^ (r0 & 7);
    const int r1 = slot1 >> 3, cs1 = (slot1 & 7) ^ (r1 & 7);
    const bf16_t* Kg0 = K + (size_t)r0 * DK_ + cs0 * 8;
    const bf16_t* Kg1 = K + (size_t)r1 * DK_ + cs1 * 8;
    const int off0 = __builtin_amdgcn_readfirstlane((w << 6) * 8);       // elems
    const int off1 = __builtin_amdgcn_readfirstlane(((w << 6) + 256) * 8);
    const uint32_t rm = (uint32_t)((c & 7) << 4);

    gload16(Kg0, &Kbuf[0][off0]);
    gload16(Kg1, &Kbuf[0][off1]);
    gload16(Kg0 + (size_t)TILE * DK_, &Kbuf[1][off0]);
    gload16(Kg1 + (size_t)TILE * DK_, &Kbuf[1][off1]);
    asm volatile("s_waitcnt vmcnt(2)" ::: "memory");
    __builtin_amdgcn_s_barrier();

    float l_r = 0.f;
    int bc = 0;
    for (int t = 0; t < NT; ++t) {
        if (t + 2 < NT) {
            int b2 = bc + 2; if (b2 >= 3) b2 -= 3;
            gload16(Kg0 + (size_t)(t + 2) * TILE * DK_, &Kbuf[b2][off0]);
            gload16(Kg1 + (size_t)(t + 2) * TILE * DK_, &Kbuf[b2][off1]);
        }
        __builtin_amdgcn_sched_barrier(0);
        u16 m16 = (u16)(mreg[t >> 2] >> ((t & 3) << 4));
        const char* kb = (const char*)&Kbuf[bc][0];
        f32x4 acc[4] = {};
        __builtin_amdgcn_s_setprio(1);
#pragma unroll
        for (int tk = 0; tk < 4; ++tk) {
            uint32_t base = (uint32_t)((tk * 16 + c) * 128 + g * 16);
            bf16x8 a0 = *reinterpret_cast<const bf16x8*>(kb + (base ^ rm));
            bf16x8 a1 = *reinterpret_cast<const bf16x8*>(kb + ((base + 64) ^ rm));
            acc[tk] = MFMA16(a0, qf0, acc[tk]);
            acc[tk] = MFMA16(a1, qf1, acc[tk]);
        }
        __builtin_amdgcn_s_setprio(0);
        float ps = 0.f;
#pragma unroll
        for (int tk = 0; tk < 4; ++tk) {
#pragma unroll
            for (int r = 0; r < 4; ++r) {
                float e = __expf(acc[tk][r] * 0.125f);
                e = ((m16 >> (tk * 4 + r)) & 1) ? e : 0.f;
                ps += e;
            }
        }
        l_r += ps;
        if (t + 2 < NT) asm volatile("s_waitcnt vmcnt(2)" ::: "memory");
        else            asm volatile("s_waitcnt vmcnt(0)" ::: "memory");
        __builtin_amdgcn_sched_barrier(0);
        __builtin_amdgcn_s_barrier();
        bc = (bc == 2) ? 0 : bc + 1;
    }
    l_r += __shfl_xor(l_r, 16);
    l_r += __shfl_xor(l_r, 32);
    if (l < 16) linv[(size_t)bh * S_ + q0 + l] = 1.0f / l_r;
}

// ---------------------------------------------------------------------------
// attn_emit: pass 2. Reads precomputed inv_l; emits NT-coalesced attn + PV.
// ---------------------------------------------------------------------------
__global__ __launch_bounds__(512) void attn_emit(
        const bf16_t* __restrict__ qh, const bf16_t* __restrict__ kh,
        const bf16_t* __restrict__ vt, const u16* __restrict__ bits2,
        const float* __restrict__ linv,
        float* __restrict__ attn, bf16_t* __restrict__ ctx)
{
    constexpr int TILE = 64;
    constexpr int NT = S_ / TILE;
    __shared__ bf16_t Kbuf[3][TILE * DK_];
    __shared__ bf16_t Vbuf[3][TILE * DK_];
    __shared__ float  Pf[8][16 * 64];

    const int tid = threadIdx.x;
    const int w = tid >> 6, l = tid & 63;
    const int c = l & 15, g = l >> 4;

    const int id = blockIdx.x;
    const int xcd = id & 7, ixd = id >> 3;
    const int bh = xcd * 4 + (ixd >> 4);
    const int qt = ixd & 15;
    const int q0 = qt * 128 + w * 16;
    const int b = bh >> 4, h = bh & 15;

    const bf16_t* Q = qh + ((size_t)bh * S_ + q0) * DK_;
    const bf16_t* K = kh + (size_t)bh * S_ * DK_;
    const bf16_t* V = vt + (size_t)bh * DK_ * S_;
    float* Astrip = attn + ((size_t)bh * S_ + q0) * S_;

    u64 mreg[8];
    {
        const u64* mp = reinterpret_cast<const u64*>(
            bits2 + (((size_t)b * S_ + q0 + c) * 4 + g) * 32);
#pragma unroll
        for (int i = 0; i < 8; ++i) mreg[i] = mp[i];
    }

    bf16x8 qf0 = *reinterpret_cast<const bf16x8*>(&Q[c * DK_ + g * 8]);
    bf16x8 qf1 = *reinterpret_cast<const bf16x8*>(&Q[c * DK_ + 32 + g * 8]);
    const float inv_l = linv[(size_t)bh * S_ + q0 + c];

    const int row_s = (w << 3) + (l >> 3);
    const int csx = (l & 7) ^ (row_s & 7);
    const bf16_t* Kg = K + (size_t)row_s * DK_ + csx * 8;
    const bf16_t* Vg = V + (size_t)row_s * S_ + csx * 8;
    const int woffu = __builtin_amdgcn_readfirstlane(w * 512);
    const uint32_t rm = (uint32_t)((c & 7) << 4);
    const uint32_t xr = (uint32_t)((c & 7) << 4);

    gload16(Kg, &Kbuf[0][woffu]);
    gload16(Vg, &Vbuf[0][woffu]);
    gload16(Kg + (size_t)TILE * DK_, &Kbuf[1][woffu]);
    gload16(Vg + TILE, &Vbuf[1][woffu]);
    asm volatile("s_waitcnt vmcnt(2)" ::: "memory");
    __builtin_amdgcn_s_barrier();

    float* pf = &Pf[w][0];
    f32x4 oacc[4] = {};
    int bc = 0;
    for (int t = 0; t < NT; ++t) {
        if (t + 2 < NT) {
            int b2 = bc + 2; if (b2 >= 3) b2 -= 3;
            gload16(Kg + (size_t)(t + 2) * TILE * DK_, &Kbuf[b2][woffu]);
            gload16(Vg + (t + 2) * TILE, &Vbuf[b2][woffu]);
        }
        __builtin_amdgcn_sched_barrier(0);
        u16 m16 = (u16)(mreg[t >> 2] >> ((t & 3) << 4));
        const char* kb = (const char*)&Kbuf[bc][0];
        const char* vb = (const char*)&Vbuf[bc][0];
        f32x4 acc[4] = {};
        __builtin_amdgcn_s_setprio(1);
#pragma unroll
        for (int tk = 0; tk < 4; ++tk) {
            uint32_t base = (uint32_t)((tk * 16 + c) * 128 + g * 16);
            bf16x8 a0 = *reinterpret_cast<const bf16x8*>(kb + (base ^ rm));
            bf16x8 a1 = *reinterpret_cast<const bf16x8*>(kb + ((base + 64) ^ rm));
            acc[tk] = MFMA16(a0, qf0, acc[tk]);
            acc[tk] = MFMA16(a1, qf1, acc[tk]);
        }
        __builtin_amdgcn_s_setprio(0);
#pragma unroll
        for (int tk = 0; tk < 4; ++tk) {
            f32x4 pv;
#pragma unroll
            for (int r = 0; r < 4; ++r) {
                float p = __expf(acc[tk][r] * 0.125f) * inv_l;
                pv[r] = ((m16 >> (tk * 4 + r)) & 1) ? p : 0.f;
            }
            *reinterpret_cast<f32x4*>((char*)pf + ((uint32_t)(c * 256 + tk * 64 + g * 16) ^ xr)) = pv;
        }
        asm volatile("s_waitcnt lgkmcnt(0)" ::: "memory");
        __builtin_amdgcn_sched_barrier(0);
#pragma unroll
        for (int i = 0; i < 4; ++i) {
            int row = i * 4 + (l >> 4);
            uint32_t off = (uint32_t)(i * 1024 + l * 16) ^ (uint32_t)((row & 7) << 4);
            f32x4 sv = *reinterpret_cast<const f32x4*>((char*)pf + off);
            __builtin_nontemporal_store(sv,
                reinterpret_cast<f32x4*>(Astrip + (size_t)row * S_ + t * TILE + (l & 15) * 4));
        }
        f32x4 p0a = *reinterpret_cast<const f32x4*>((char*)pf + ((uint32_t)(c * 256 + g * 32) ^ xr));
        f32x4 p0b = *reinterpret_cast<const f32x4*>((char*)pf + ((uint32_t)(c * 256 + g * 32 + 16) ^ xr));
        f32x4 p1a = *reinterpret_cast<const f32x4*>((char*)pf + ((uint32_t)(c * 256 + 128 + g * 32) ^ xr));
        f32x4 p1b = *reinterpret_cast<const f32x4*>((char*)pf + ((uint32_t)(c * 256 + 128 + g * 32 + 16) ^ xr));
        bf16x8 pa0 = { (bf16_t)p0a[0], (bf16_t)p0a[1], (bf16_t)p0a[2], (bf16_t)p0a[3],
                       (bf16_t)p0b[0], (bf16_t)p0b[1], (bf16_t)p0b[2], (bf16_t)p0b[3] };
        bf16x8 pa1 = { (bf16_t)p1a[0], (bf16_t)p1a[1], (bf16_t)p1a[2], (bf16_t)p1a[3],
                       (bf16_t)p1b[0], (bf16_t)p1b[1], (bf16_t)p1b[2], (bf16_t)p1b[3] };
        __builtin_amdgcn_s_setprio(1);
#pragma unroll
        for (int tk = 0; tk < 4; ++tk) {
            uint32_t base = (uint32_t)((tk * 16 + c) * 128 + g * 16);
            bf16x8 b0 = *reinterpret_cast<const bf16x8*>(vb + (base ^ rm));
            bf16x8 b1 = *reinterpret_cast<const bf16x8*>(vb + ((base + 64) ^ rm));
            oacc[tk] = MFMA16(pa0, b0, oacc[tk]);
            oacc[tk] = MFMA16(pa1, b1, oacc[tk]);
        }
        __builtin_amdgcn_s_setprio(0);
        if (t + 2 < NT)       asm volatile("s_waitcnt vmcnt(6)" ::: "memory");
        else if (t + 1 < NT)  asm volatile("s_waitcnt vmcnt(4)" ::: "memory");
        asm volatile("s_waitcnt lgkmcnt(0)" ::: "memory");
        __builtin_amdgcn_sched_barrier(0);
        __builtin_amdgcn_s_barrier();
        bc = (bc == 2) ? 0 : bc + 1;
    }

#pragma unroll
    for (int tk = 0; tk < 4; ++tk) {
#pragma unroll
        for (int r = 0; r < 4; ++r) {
            int qrow = q0 + g * 4 + r;
            ctx[((size_t)b * S_ + qrow) * D_ + h * DK_ + tk * 16 + c] = (bf16_t)oacc[tk][r];
        }
    }
}

// ---------------------------------------------------------------------------
// LayerNorm over last dim (1024), 4096 rows
// ---------------------------------------------------------------------------
__global__ void ln_kernel(const float* __restrict__ x, const float* __restrict__ gamma,
                          const float* __restrict__ beta, float* __restrict__ out)
{
    int row = blockIdx.x;
    const float* xr = x + (size_t)row * D_;
    int tid = threadIdx.x;
    float v[4];
    float s = 0.f;
#pragma unroll
    for (int i = 0; i < 4; ++i) {
        v[i] = xr[tid + i * 256];
        s += v[i];
    }
#pragma unroll
    for (int off = 32; off > 0; off >>= 1) s += __shfl_xor(s, off);
    __shared__ float red[4];
    int wid = tid >> 6, lane = tid & 63;
    if (lane == 0) red[wid] = s;
    __syncthreads();
    float mu = (red[0] + red[1] + red[2] + red[3]) * (1.0f / D_);
    float vs = 0.f;
#pragma unroll
    for (int i = 0; i < 4; ++i) {
        float d = v[i] - mu;
        vs += d * d;
    }
#pragma unroll
    for (int off = 32; off > 0; off >>= 1) vs += __shfl_xor(vs, off);
    __syncthreads();
    __shared__ float red2[4];
    if (lane == 0) red2[wid] = vs;
    __syncthreads();
    float var = (red2[0] + red2[1] + red2[2] + red2[3]) * (1.0f / D_);
    float rs = rsqrtf(var + EPS_);
#pragma unroll
    for (int i = 0; i < 4; ++i) {
        int c = tid + i * 256;
        out[(size_t)row * D_ + c] = (v[i] - mu) * rs * gamma[c] + beta[c];
    }
}

extern "C" void kernel_launch(void* const* d_in, const int* in_sizes, int n_in,
                              void* d_out, int out_size, void* d_ws, size_t ws_size,
                              hipStream_t stream) {
    const float* q    = (const float*)d_in[0];
    const float* k    = (const float*)d_in[1];
    const float* v    = (const float*)d_in[2];
    const int*   mask = (const int*)d_in[3];
    const float* Wq   = (const float*)d_in[4];
    const float* bq   = (const float*)d_in[5];
    const float* Wk   = (const float*)d_in[6];
    const float* bk   = (const float*)d_in[7];
    const float* Wv   = (const float*)d_in[8];
    const float* bv   = (const float*)d_in[9];
    const float* Wo   = (const float*)d_in[10];
    const float* bo   = (const float*)d_in[11];
    const float* gamma= (const float*)d_in[12];
    const float* beta = (const float*)d_in[13];

    float* out  = (float*)d_out;                       // [B,S,D]
    float* attn = out + (size_t)B_ * S_ * D_;          // [B,H,S,S]

    uint8_t* ws = (uint8_t*)d_ws;
    bf16_t* xq  = (bf16_t*)(ws);
    bf16_t* xk  = (bf16_t*)(ws + ((size_t)8  << 20));
    bf16_t* xv  = (bf16_t*)(ws + ((size_t)16 << 20));
    bf16_t* wqb = (bf16_t*)(ws + ((size_t)24 << 20));
    bf16_t* wkb = (bf16_t*)(ws + ((size_t)26 << 20));
    bf16_t* wvb = (bf16_t*)(ws + ((size_t)28 << 20));
    bf16_t* wob = (bf16_t*)(ws + ((size_t)30 << 20));
    bf16_t* qh  = (bf16_t*)(ws + ((size_t)32 << 20));
    u16*    bits= (u16*)   (ws + ((size_t)40 << 20));  // 1 MB
    float*  linv= (float*) (ws + ((size_t)41 << 20));  // 256 KB
    bf16_t* kh  = (bf16_t*)(ws + ((size_t)42 << 20));
    bf16_t* vt  = (bf16_t*)(ws + ((size_t)50 << 20));
    bf16_t* ctx = (bf16_t*)(ws);                       // over xq (dead)
    float*  x   = (float*) (ws + ((size_t)8 << 20));   // over xk+xv (dead)

    dim3 blk(256);
    prep<<<dim3(40960), blk, 0, stream>>>(mask, bits, q, k, v, xq, xk, xv,
                                          Wq, Wk, Wv, Wo, wqb, wkb, wvb, wob);

    dim3 gqkv(D_ / 128, (B_ * S_) / 128, 3);           // (8, 32, 3)
    qkv_gemm<<<gqkv, blk, 0, stream>>>(xq, xk, xv, wqb, wkb, wvb,
                                       bq, bk, bv, qh, kh, vt);

    attn_stats<<<dim3(1024), blk, 0, stream>>>(qh, kh, bits, linv);
    attn_emit<<<dim3(512), dim3(512), 0, stream>>>(qh, kh, vt, bits, linv, attn, ctx);

    dim3 ggemm(D_ / 128, (B_ * S_) / 128);             // (8, 32)
    oproj_gemm<<<ggemm, blk, 0, stream>>>(ctx, wob, bo, q, x);
    ln_kernel<<<dim3(B_ * S_), blk, 0, stream>>>(x, gamma, beta, out);
}

// Round 14
// 265.203 us; speedup vs baseline: 1.0677x; 1.0677x over previous
//
#include <hip/hip_runtime.h>
#include <math.h>

#define B_ 2
#define S_ 2048
#define D_ 1024
#define H_ 16
#define DK_ 64
#define EPS_ 1e-5f

typedef __bf16 bf16_t;
typedef __bf16 bf16x4 __attribute__((ext_vector_type(4)));
typedef __bf16 bf16x8 __attribute__((ext_vector_type(8)));
typedef float f32x4 __attribute__((ext_vector_type(4)));
typedef unsigned long long u64;
typedef unsigned short u16;

#define MFMA16(a, b, c) __builtin_amdgcn_mfma_f32_16x16x32_bf16(a, b, c, 0, 0, 0)

__device__ __forceinline__ void gload16(const bf16_t* g, bf16_t* l) {
    __builtin_amdgcn_global_load_lds(
        (const __attribute__((address_space(1))) void*)g,
        (__attribute__((address_space(3))) void*)l, 16, 0, 0);
}

// ---------------------------------------------------------------------------
// Fused prologue: one launch, three regions (mask_pack | cvt q,k,v | cvt W*).
// ---------------------------------------------------------------------------
__global__ __launch_bounds__(256) void prep(
        const int* __restrict__ mask, u16* __restrict__ bits2,
        const float* __restrict__ q, const float* __restrict__ k,
        const float* __restrict__ v,
        bf16_t* __restrict__ xq, bf16_t* __restrict__ xk, bf16_t* __restrict__ xv,
        const float* __restrict__ Wq, const float* __restrict__ Wk,
        const float* __restrict__ Wv, const float* __restrict__ Wo,
        bf16_t* __restrict__ wq, bf16_t* __restrict__ wk,
        bf16_t* __restrict__ wv, bf16_t* __restrict__ wo)
{
    int bid = blockIdx.x;
    if (bid < 32768) {
        size_t i = (size_t)bid * 256 + threadIdx.x;
        int m = mask[i];
        u64 wm = __ballot(m != 0);
        if ((threadIdx.x & 63) == 0) {
            size_t widx = i >> 6;
            size_t row = widx >> 5;
            int t = (int)(widx & 31);
#pragma unroll
            for (int g = 0; g < 4; ++g) {
                u16 val = 0;
#pragma unroll
                for (int tk = 0; tk < 4; ++tk)
                    val |= (u16)(((wm >> (tk * 16 + g * 4)) & 0xF) << (tk * 4));
                bits2[(row * 4 + g) * 32 + t] = val;
            }
        }
    } else if (bid < 38912) {
        int b2 = bid - 32768;                  // 6144 blocks: q,k,v (2048 each)
        int region = b2 >> 11;
        int i = ((b2 & 2047) << 8) + threadIdx.x;
        const float* in = (region == 0) ? q : (region == 1) ? k : v;
        bf16_t* out = (region == 0) ? xq : (region == 1) ? xk : xv;
        float4 v0 = reinterpret_cast<const float4*>(in)[i * 2];
        float4 v1 = reinterpret_cast<const float4*>(in)[i * 2 + 1];
        bf16x8 o = { (bf16_t)v0.x, (bf16_t)v0.y, (bf16_t)v0.z, (bf16_t)v0.w,
                     (bf16_t)v1.x, (bf16_t)v1.y, (bf16_t)v1.z, (bf16_t)v1.w };
        reinterpret_cast<bf16x8*>(out)[i] = o;
    } else {
        int b2 = bid - 38912;                  // 2048 blocks: Wq,Wk,Wv,Wo (512 each)
        int region = b2 >> 9;
        int i = ((b2 & 511) << 8) + threadIdx.x;
        const float* in = (region == 0) ? Wq : (region == 1) ? Wk : (region == 2) ? Wv : Wo;
        bf16_t* out = (region == 0) ? wq : (region == 1) ? wk : (region == 2) ? wv : wo;
        float4 v0 = reinterpret_cast<const float4*>(in)[i * 2];
        float4 v1 = reinterpret_cast<const float4*>(in)[i * 2 + 1];
        bf16x8 o = { (bf16_t)v0.x, (bf16_t)v0.y, (bf16_t)v0.z, (bf16_t)v0.w,
                     (bf16_t)v1.x, (bf16_t)v1.y, (bf16_t)v1.z, (bf16_t)v1.w };
        reinterpret_cast<bf16x8*>(out)[i] = o;
    }
}

// ---------------------------------------------------------------------------
// Shared 128x128 GEMM body.
// ---------------------------------------------------------------------------
__device__ __forceinline__ void gemm_body(
        const bf16_t* __restrict__ Asrc, const bf16_t* __restrict__ Bsrc,
        const float* __restrict__ bias, const float* __restrict__ resid,
        float* __restrict__ xout, bf16_t* __restrict__ bout,
        int mode, int m0, int n0)
{
    __shared__ bf16_t As[128 * 64];
    __shared__ bf16_t Bs[128 * 64];
    const int tid = threadIdx.x;
    const int w = tid >> 6, l = tid & 63;
    const int c = l & 15, g = l >> 4;
    const int wr = w >> 1, wc = w & 1;

    int srow[4], scol[4];
    uint32_t soff[4];
#pragma unroll
    for (int i = 0; i < 4; ++i) {
        int s = tid + i * 256;
        srow[i] = s >> 3;
        scol[i] = s & 7;
        soff[i] = (uint32_t)(s * 16) ^ (uint32_t)((srow[i] & 7) << 4);
    }

    bf16x8 areg[4], breg[4];
#pragma unroll
    for (int i = 0; i < 4; ++i) {
        areg[i] = *reinterpret_cast<const bf16x8*>(Asrc + (size_t)srow[i] * D_ + scol[i] * 8);
        breg[i] = *reinterpret_cast<const bf16x8*>(Bsrc + (size_t)srow[i] * D_ + scol[i] * 8);
    }

    f32x4 acc[4][4] = {};
    for (int kt = 0; kt < 16; ++kt) {
#pragma unroll
        for (int i = 0; i < 4; ++i) {
            *reinterpret_cast<bf16x8*>((char*)As + soff[i]) = areg[i];
            *reinterpret_cast<bf16x8*>((char*)Bs + soff[i]) = breg[i];
        }
        __syncthreads();
        if (kt + 1 < 16) {
            int k0 = (kt + 1) * 64;
#pragma unroll
            for (int i = 0; i < 4; ++i) {
                areg[i] = *reinterpret_cast<const bf16x8*>(Asrc + (size_t)srow[i] * D_ + k0 + scol[i] * 8);
                breg[i] = *reinterpret_cast<const bf16x8*>(Bsrc + (size_t)srow[i] * D_ + k0 + scol[i] * 8);
            }
        }
        bf16x8 bf0[4], bf1[4];
#pragma unroll
        for (int j = 0; j < 4; ++j) {
            int R = wc * 64 + j * 16 + c;
            const char* base = (const char*)Bs + R * 128;
            uint32_t msk = (uint32_t)((R & 7) << 4);
            bf0[j] = *reinterpret_cast<const bf16x8*>(base + ((g * 16) ^ msk));
            bf1[j] = *reinterpret_cast<const bf16x8*>(base + ((64 + g * 16) ^ msk));
        }
#pragma unroll
        for (int i = 0; i < 4; ++i) {
            int R = wr * 64 + i * 16 + c;
            const char* base = (const char*)As + R * 128;
            uint32_t msk = (uint32_t)((R & 7) << 4);
            bf16x8 a0 = *reinterpret_cast<const bf16x8*>(base + ((g * 16) ^ msk));
            bf16x8 a1 = *reinterpret_cast<const bf16x8*>(base + ((64 + g * 16) ^ msk));
#pragma unroll
            for (int j = 0; j < 4; ++j) {
                acc[i][j] = MFMA16(a0, bf0[j], acc[i][j]);
                acc[i][j] = MFMA16(a1, bf1[j], acc[i][j]);
            }
        }
        __syncthreads();
    }

#pragma unroll
    for (int i = 0; i < 4; ++i) {
#pragma unroll
        for (int j = 0; j < 4; ++j) {
#pragma unroll
            for (int r = 0; r < 4; ++r) {
                int P  = wr * 64 + i * 16 + g * 4 + r;
                int Qd = wc * 64 + j * 16 + c;
                float val = acc[i][j][r];
                if (mode == 2) {
                    int m = m0 + P, n = n0 + Qd;
                    xout[(size_t)m * D_ + n] = val + bias[n] + resid[(size_t)m * D_ + n];
                } else if (mode == 0) {
                    int m = m0 + P, n = n0 + Qd;
                    int bb = m >> 11, s = m & (S_ - 1);
                    int h = n >> 6, dk = n & 63;
                    bout[(((size_t)bb * H_ + h) * S_ + s) * DK_ + dk] = (bf16_t)(val + bias[n]);
                } else {
                    int n = n0 + P, m = m0 + Qd;
                    int bb = m >> 11, s = m & (S_ - 1);
                    int h = n >> 6, dk = n & 63;
                    bout[(((size_t)bb * H_ + h) * DK_ + dk) * S_ + s] = (bf16_t)(val + bias[n]);
                }
            }
        }
    }
}

__global__ __launch_bounds__(256) void qkv_gemm(
        const bf16_t* __restrict__ xq, const bf16_t* __restrict__ xk,
        const bf16_t* __restrict__ xv,
        const bf16_t* __restrict__ wq, const bf16_t* __restrict__ wk,
        const bf16_t* __restrict__ wv,
        const float* __restrict__ bq, const float* __restrict__ bk,
        const float* __restrict__ bv,
        bf16_t* __restrict__ qh, bf16_t* __restrict__ kh, bf16_t* __restrict__ vt)
{
    const int z = blockIdx.z;
    const int m0 = blockIdx.y * 128, n0 = blockIdx.x * 128;
    const bf16_t* X = (z == 0) ? xq : (z == 1) ? xk : xv;
    const bf16_t* W = (z == 0) ? wq : (z == 1) ? wk : wv;
    const float* bias = (z == 0) ? bq : (z == 1) ? bk : bv;
    bf16_t* out = (z == 0) ? qh : (z == 1) ? kh : vt;
    int mode = (z == 2) ? 1 : 0;
    const bf16_t* Asrc = (mode == 1) ? (W + (size_t)n0 * D_) : (X + (size_t)m0 * D_);
    const bf16_t* Bsrc = (mode == 1) ? (X + (size_t)m0 * D_) : (W + (size_t)n0 * D_);
    gemm_body(Asrc, Bsrc, bias, nullptr, nullptr, out, mode, m0, n0);
}

__global__ __launch_bounds__(256) void oproj_gemm(
        const bf16_t* __restrict__ ctx, const bf16_t* __restrict__ wo,
        const float* __restrict__ bo, const float* __restrict__ resid,
        float* __restrict__ x)
{
    const int m0 = blockIdx.y * 128, n0 = blockIdx.x * 128;
    gemm_body(ctx + (size_t)m0 * D_, wo + (size_t)n0 * D_, bo, resid, x, nullptr, 2, m0, n0);
}

// ---------------------------------------------------------------------------
// Fused attention (r12 config exactly): no-max softmax, K/V via
// global_load_lds, 3-deep buffers, counted vmcnt, Pf fp32-LDS coalescing,
// NONTEMPORAL coalesced attn stores, both passes in one kernel so blocks
// at different phases overlap on the CU.
// ---------------------------------------------------------------------------
__global__ __launch_bounds__(512) void fused_attn(
        const bf16_t* __restrict__ qh,   // [B,H,S,DK]
        const bf16_t* __restrict__ kh,   // [B,H,S,DK]
        const bf16_t* __restrict__ vt,   // [B,H,DK,S]
        const u16*    __restrict__ bits2,// [B*S*4][32] u16
        float* __restrict__ attn,        // [B,H,S,S]
        bf16_t* __restrict__ ctx)        // [B,S,D] bf16
{
    constexpr int TILE = 64;
    constexpr int NT = S_ / TILE;        // 32
    __shared__ bf16_t Kbuf[3][TILE * DK_];
    __shared__ bf16_t Vbuf[3][TILE * DK_];
    __shared__ float  Pf[8][16 * 64];

    const int tid = threadIdx.x;
    const int w = tid >> 6, l = tid & 63;
    const int c = l & 15, g = l >> 4;

    const int id = blockIdx.x;
    const int xcd = id & 7, ixd = id >> 3;
    const int bh = xcd * 4 + (ixd >> 4);
    const int qt = ixd & 15;
    const int q0 = qt * 128 + w * 16;
    const int b = bh >> 4, h = bh & 15;

    const bf16_t* Q = qh + ((size_t)bh * S_ + q0) * DK_;
    const bf16_t* K = kh + (size_t)bh * S_ * DK_;
    const bf16_t* V = vt + (size_t)bh * DK_ * S_;
    float* Astrip = attn + ((size_t)bh * S_ + q0) * S_;

    u64 mreg[8];
    {
        const u64* mp = reinterpret_cast<const u64*>(
            bits2 + (((size_t)b * S_ + q0 + c) * 4 + g) * 32);
#pragma unroll
        for (int i = 0; i < 8; ++i) mreg[i] = mp[i];
    }

    bf16x8 qf0 = *reinterpret_cast<const bf16x8*>(&Q[c * DK_ + g * 8]);
    bf16x8 qf1 = *reinterpret_cast<const bf16x8*>(&Q[c * DK_ + 32 + g * 8]);

    const int row_s = (w << 3) + (l >> 3);
    const int csx = (l & 7) ^ (row_s & 7);
    const bf16_t* Kg = K + (size_t)row_s * DK_ + csx * 8;
    const bf16_t* Vg = V + (size_t)row_s * S_ + csx * 8;
    const int woffu = __builtin_amdgcn_readfirstlane(w * 512);
    const uint32_t rm = (uint32_t)((c & 7) << 4);
    const uint32_t xr = (uint32_t)((c & 7) << 4);

    //================= pass 1: row sums of exp =================
    gload16(Kg, &Kbuf[0][woffu]);
    gload16(Kg + (size_t)TILE * DK_, &Kbuf[1][woffu]);
    asm volatile("s_waitcnt vmcnt(1)" ::: "memory");
    __builtin_amdgcn_s_barrier();

    float l_r = 0.f;
    int bc = 0;
    for (int t = 0; t < NT; ++t) {
        if (t + 2 < NT) {
            int b2 = bc + 2; if (b2 >= 3) b2 -= 3;
            gload16(Kg + (size_t)(t + 2) * TILE * DK_, &Kbuf[b2][woffu]);
        }
        __builtin_amdgcn_sched_barrier(0);
        u16 m16 = (u16)(mreg[t >> 2] >> ((t & 3) << 4));
        const char* kb = (const char*)&Kbuf[bc][0];
        f32x4 acc[4] = {};
        __builtin_amdgcn_s_setprio(1);
#pragma unroll
        for (int tk = 0; tk < 4; ++tk) {
            uint32_t base = (uint32_t)((tk * 16 + c) * 128 + g * 16);
            bf16x8 a0 = *reinterpret_cast<const bf16x8*>(kb + (base ^ rm));
            bf16x8 a1 = *reinterpret_cast<const bf16x8*>(kb + ((base + 64) ^ rm));
            acc[tk] = MFMA16(a0, qf0, acc[tk]);
            acc[tk] = MFMA16(a1, qf1, acc[tk]);
        }
        __builtin_amdgcn_s_setprio(0);
        float ps = 0.f;
#pragma unroll
        for (int tk = 0; tk < 4; ++tk) {
#pragma unroll
            for (int r = 0; r < 4; ++r) {
                float e = __expf(acc[tk][r] * 0.125f);
                e = ((m16 >> (tk * 4 + r)) & 1) ? e : 0.f;
                ps += e;
            }
        }
        l_r += ps;
        if (t + 2 < NT) asm volatile("s_waitcnt vmcnt(1)" ::: "memory");
        else            asm volatile("s_waitcnt vmcnt(0)" ::: "memory");
        asm volatile("s_waitcnt lgkmcnt(0)" ::: "memory");
        __builtin_amdgcn_sched_barrier(0);
        __builtin_amdgcn_s_barrier();
        bc = (bc == 2) ? 0 : bc + 1;
    }
    l_r += __shfl_xor(l_r, 16);
    l_r += __shfl_xor(l_r, 32);
    const float inv_l = 1.0f / l_r;

    //================= pass 2: emit P + PV =================
    gload16(Kg, &Kbuf[0][woffu]);
    gload16(Vg, &Vbuf[0][woffu]);
    gload16(Kg + (size_t)TILE * DK_, &Kbuf[1][woffu]);
    gload16(Vg + TILE, &Vbuf[1][woffu]);
    asm volatile("s_waitcnt vmcnt(2)" ::: "memory");
    __builtin_amdgcn_s_barrier();

    float* pf = &Pf[w][0];
    f32x4 oacc[4] = {};
    bc = 0;
    for (int t = 0; t < NT; ++t) {
        if (t + 2 < NT) {
            int b2 = bc + 2; if (b2 >= 3) b2 -= 3;
            gload16(Kg + (size_t)(t + 2) * TILE * DK_, &Kbuf[b2][woffu]);
            gload16(Vg + (t + 2) * TILE, &Vbuf[b2][woffu]);
        }
        __builtin_amdgcn_sched_barrier(0);
        u16 m16 = (u16)(mreg[t >> 2] >> ((t & 3) << 4));
        const char* kb = (const char*)&Kbuf[bc][0];
        const char* vb = (const char*)&Vbuf[bc][0];
        f32x4 acc[4] = {};
        __builtin_amdgcn_s_setprio(1);
#pragma unroll
        for (int tk = 0; tk < 4; ++tk) {
            uint32_t base = (uint32_t)((tk * 16 + c) * 128 + g * 16);
            bf16x8 a0 = *reinterpret_cast<const bf16x8*>(kb + (base ^ rm));
            bf16x8 a1 = *reinterpret_cast<const bf16x8*>(kb + ((base + 64) ^ rm));
            acc[tk] = MFMA16(a0, qf0, acc[tk]);
            acc[tk] = MFMA16(a1, qf1, acc[tk]);
        }
        __builtin_amdgcn_s_setprio(0);
#pragma unroll
        for (int tk = 0; tk < 4; ++tk) {
            f32x4 pv;
#pragma unroll
            for (int r = 0; r < 4; ++r) {
                float p = __expf(acc[tk][r] * 0.125f) * inv_l;
                pv[r] = ((m16 >> (tk * 4 + r)) & 1) ? p : 0.f;
            }
            *reinterpret_cast<f32x4*>((char*)pf + ((uint32_t)(c * 256 + tk * 64 + g * 16) ^ xr)) = pv;
        }
        asm volatile("s_waitcnt lgkmcnt(0)" ::: "memory");
        __builtin_amdgcn_sched_barrier(0);
#pragma unroll
        for (int i = 0; i < 4; ++i) {
            int row = i * 4 + (l >> 4);
            uint32_t off = (uint32_t)(i * 1024 + l * 16) ^ (uint32_t)((row & 7) << 4);
            f32x4 sv = *reinterpret_cast<const f32x4*>((char*)pf + off);
            __builtin_nontemporal_store(sv,
                reinterpret_cast<f32x4*>(Astrip + (size_t)row * S_ + t * TILE + (l & 15) * 4));
        }
        f32x4 p0a = *reinterpret_cast<const f32x4*>((char*)pf + ((uint32_t)(c * 256 + g * 32) ^ xr));
        f32x4 p0b = *reinterpret_cast<const f32x4*>((char*)pf + ((uint32_t)(c * 256 + g * 32 + 16) ^ xr));
        f32x4 p1a = *reinterpret_cast<const f32x4*>((char*)pf + ((uint32_t)(c * 256 + 128 + g * 32) ^ xr));
        f32x4 p1b = *reinterpret_cast<const f32x4*>((char*)pf + ((uint32_t)(c * 256 + 128 + g * 32 + 16) ^ xr));
        bf16x8 pa0 = { (bf16_t)p0a[0], (bf16_t)p0a[1], (bf16_t)p0a[2], (bf16_t)p0a[3],
                       (bf16_t)p0b[0], (bf16_t)p0b[1], (bf16_t)p0b[2], (bf16_t)p0b[3] };
        bf16x8 pa1 = { (bf16_t)p1a[0], (bf16_t)p1a[1], (bf16_t)p1a[2], (bf16_t)p1a[3],
                       (bf16_t)p1b[0], (bf16_t)p1b[1], (bf16_t)p1b[2], (bf16_t)p1b[3] };
        __builtin_amdgcn_s_setprio(1);
#pragma unroll
        for (int tk = 0; tk < 4; ++tk) {
            uint32_t base = (uint32_t)((tk * 16 + c) * 128 + g * 16);
            bf16x8 b0 = *reinterpret_cast<const bf16x8*>(vb + (base ^ rm));
            bf16x8 b1 = *reinterpret_cast<const bf16x8*>(vb + ((base + 64) ^ rm));
            oacc[tk] = MFMA16(pa0, b0, oacc[tk]);
            oacc[tk] = MFMA16(pa1, b1, oacc[tk]);
        }
        __builtin_amdgcn_s_setprio(0);
        if (t + 2 < NT)       asm volatile("s_waitcnt vmcnt(6)" ::: "memory");
        else if (t + 1 < NT)  asm volatile("s_waitcnt vmcnt(4)" ::: "memory");
        asm volatile("s_waitcnt lgkmcnt(0)" ::: "memory");
        __builtin_amdgcn_sched_barrier(0);
        __builtin_amdgcn_s_barrier();
        bc = (bc == 2) ? 0 : bc + 1;
    }

#pragma unroll
    for (int tk = 0; tk < 4; ++tk) {
#pragma unroll
        for (int r = 0; r < 4; ++r) {
            int qrow = q0 + g * 4 + r;
            ctx[((size_t)b * S_ + qrow) * D_ + h * DK_ + tk * 16 + c] = (bf16_t)oacc[tk][r];
        }
    }
}

// ---------------------------------------------------------------------------
// LayerNorm over last dim (1024), 4096 rows
// ---------------------------------------------------------------------------
__global__ void ln_kernel(const float* __restrict__ x, const float* __restrict__ gamma,
                          const float* __restrict__ beta, float* __restrict__ out)
{
    int row = blockIdx.x;
    const float* xr = x + (size_t)row * D_;
    int tid = threadIdx.x;
    float v[4];
    float s = 0.f;
#pragma unroll
    for (int i = 0; i < 4; ++i) {
        v[i] = xr[tid + i * 256];
        s += v[i];
    }
#pragma unroll
    for (int off = 32; off > 0; off >>= 1) s += __shfl_xor(s, off);
    __shared__ float red[4];
    int wid = tid >> 6, lane = tid & 63;
    if (lane == 0) red[wid] = s;
    __syncthreads();
    float mu = (red[0] + red[1] + red[2] + red[3]) * (1.0f / D_);
    float vs = 0.f;
#pragma unroll
    for (int i = 0; i < 4; ++i) {
        float d = v[i] - mu;
        vs += d * d;
    }
#pragma unroll
    for (int off = 32; off > 0; off >>= 1) vs += __shfl_xor(vs, off);
    __syncthreads();
    __shared__ float red2[4];
    if (lane == 0) red2[wid] = vs;
    __syncthreads();
    float var = (red2[0] + red2[1] + red2[2] + red2[3]) * (1.0f / D_);
    float rs = rsqrtf(var + EPS_);
#pragma unroll
    for (int i = 0; i < 4; ++i) {
        int c = tid + i * 256;
        out[(size_t)row * D_ + c] = (v[i] - mu) * rs * gamma[c] + beta[c];
    }
}

extern "C" void kernel_launch(void* const* d_in, const int* in_sizes, int n_in,
                              void* d_out, int out_size, void* d_ws, size_t ws_size,
                              hipStream_t stream) {
    const float* q    = (const float*)d_in[0];
    const float* k    = (const float*)d_in[1];
    const float* v    = (const float*)d_in[2];
    const int*   mask = (const int*)d_in[3];
    const float* Wq   = (const float*)d_in[4];
    const float* bq   = (const float*)d_in[5];
    const float* Wk   = (const float*)d_in[6];
    const float* bk   = (const float*)d_in[7];
    const float* Wv   = (const float*)d_in[8];
    const float* bv   = (const float*)d_in[9];
    const float* Wo   = (const float*)d_in[10];
    const float* bo   = (const float*)d_in[11];
    const float* gamma= (const float*)d_in[12];
    const float* beta = (const float*)d_in[13];

    float* out  = (float*)d_out;                       // [B,S,D]
    float* attn = out + (size_t)B_ * S_ * D_;          // [B,H,S,S]

    uint8_t* ws = (uint8_t*)d_ws;
    bf16_t* xq  = (bf16_t*)(ws);
    bf16_t* xk  = (bf16_t*)(ws + ((size_t)8  << 20));
    bf16_t* xv  = (bf16_t*)(ws + ((size_t)16 << 20));
    bf16_t* wqb = (bf16_t*)(ws + ((size_t)24 << 20));
    bf16_t* wkb = (bf16_t*)(ws + ((size_t)26 << 20));
    bf16_t* wvb = (bf16_t*)(ws + ((size_t)28 << 20));
    bf16_t* wob = (bf16_t*)(ws + ((size_t)30 << 20));
    bf16_t* qh  = (bf16_t*)(ws + ((size_t)32 << 20));
    u16*    bits= (u16*)   (ws + ((size_t)40 << 20));  // 1 MB
    bf16_t* kh  = (bf16_t*)(ws + ((size_t)42 << 20));
    bf16_t* vt  = (bf16_t*)(ws + ((size_t)50 << 20));
    bf16_t* ctx = (bf16_t*)(ws);                       // over xq (dead)
    float*  x   = (float*) (ws + ((size_t)8 << 20));   // over xk+xv (dead)

    dim3 blk(256);
    prep<<<dim3(40960), blk, 0, stream>>>(mask, bits, q, k, v, xq, xk, xv,
                                          Wq, Wk, Wv, Wo, wqb, wkb, wvb, wob);

    dim3 gqkv(D_ / 128, (B_ * S_) / 128, 3);           // (8, 32, 3)
    qkv_gemm<<<gqkv, blk, 0, stream>>>(xq, xk, xv, wqb, wkb, wvb,
                                       bq, bk, bv, qh, kh, vt);

    fused_attn<<<dim3(512), dim3(512), 0, stream>>>(qh, kh, vt, bits, attn, ctx);

    dim3 ggemm(D_ / 128, (B_ * S_) / 128);             // (8, 32)
    oproj_gemm<<<ggemm, blk, 0, stream>>>(ctx, wob, bo, q, x);
    ln_kernel<<<dim3(B_ * S_), blk, 0, stream>>>(x, gamma, beta, out);
}

// Round 15
// 263.234 us; speedup vs baseline: 1.0757x; 1.0075x over previous
//
#include <hip/hip_runtime.h>
#include <math.h>

#define B_ 2
#define S_ 2048
#define D_ 1024
#define H_ 16
#define DK_ 64
#define EPS_ 1e-5f

typedef __bf16 bf16_t;
typedef __bf16 bf16x4 __attribute__((ext_vector_type(4)));
typedef __bf16 bf16x8 __attribute__((ext_vector_type(8)));
typedef float f32x4 __attribute__((ext_vector_type(4)));
typedef unsigned long long u64;
typedef unsigned short u16;

#define MFMA16(a, b, c) __builtin_amdgcn_mfma_f32_16x16x32_bf16(a, b, c, 0, 0, 0)

__device__ __forceinline__ void gload16(const bf16_t* g, bf16_t* l) {
    __builtin_amdgcn_global_load_lds(
        (const __attribute__((address_space(1))) void*)g,
        (__attribute__((address_space(3))) void*)l, 16, 0, 0);
}

// ---------------------------------------------------------------------------
// Fused prologue: one launch, three regions (mask_pack | cvt q,k,v | cvt W*).
// ---------------------------------------------------------------------------
__global__ __launch_bounds__(256) void prep(
        const int* __restrict__ mask, u16* __restrict__ bits2,
        const float* __restrict__ q, const float* __restrict__ k,
        const float* __restrict__ v,
        bf16_t* __restrict__ xq, bf16_t* __restrict__ xk, bf16_t* __restrict__ xv,
        const float* __restrict__ Wq, const float* __restrict__ Wk,
        const float* __restrict__ Wv, const float* __restrict__ Wo,
        bf16_t* __restrict__ wq, bf16_t* __restrict__ wk,
        bf16_t* __restrict__ wv, bf16_t* __restrict__ wo)
{
    int bid = blockIdx.x;
    if (bid < 32768) {
        size_t i = (size_t)bid * 256 + threadIdx.x;
        int m = mask[i];
        u64 wm = __ballot(m != 0);
        if ((threadIdx.x & 63) == 0) {
            size_t widx = i >> 6;
            size_t row = widx >> 5;
            int t = (int)(widx & 31);
#pragma unroll
            for (int g = 0; g < 4; ++g) {
                u16 val = 0;
#pragma unroll
                for (int tk = 0; tk < 4; ++tk)
                    val |= (u16)(((wm >> (tk * 16 + g * 4)) & 0xF) << (tk * 4));
                bits2[(row * 4 + g) * 32 + t] = val;
            }
        }
    } else if (bid < 38912) {
        int b2 = bid - 32768;                  // 6144 blocks: q,k,v (2048 each)
        int region = b2 >> 11;
        int i = ((b2 & 2047) << 8) + threadIdx.x;
        const float* in = (region == 0) ? q : (region == 1) ? k : v;
        bf16_t* out = (region == 0) ? xq : (region == 1) ? xk : xv;
        float4 v0 = reinterpret_cast<const float4*>(in)[i * 2];
        float4 v1 = reinterpret_cast<const float4*>(in)[i * 2 + 1];
        bf16x8 o = { (bf16_t)v0.x, (bf16_t)v0.y, (bf16_t)v0.z, (bf16_t)v0.w,
                     (bf16_t)v1.x, (bf16_t)v1.y, (bf16_t)v1.z, (bf16_t)v1.w };
        reinterpret_cast<bf16x8*>(out)[i] = o;
    } else {
        int b2 = bid - 38912;                  // 2048 blocks: Wq,Wk,Wv,Wo (512 each)
        int region = b2 >> 9;
        int i = ((b2 & 511) << 8) + threadIdx.x;
        const float* in = (region == 0) ? Wq : (region == 1) ? Wk : (region == 2) ? Wv : Wo;
        bf16_t* out = (region == 0) ? wq : (region == 1) ? wk : (region == 2) ? wv : wo;
        float4 v0 = reinterpret_cast<const float4*>(in)[i * 2];
        float4 v1 = reinterpret_cast<const float4*>(in)[i * 2 + 1];
        bf16x8 o = { (bf16_t)v0.x, (bf16_t)v0.y, (bf16_t)v0.z, (bf16_t)v0.w,
                     (bf16_t)v1.x, (bf16_t)v1.y, (bf16_t)v1.z, (bf16_t)v1.w };
        reinterpret_cast<bf16x8*>(out)[i] = o;
    }
}

// ---------------------------------------------------------------------------
// Shared 128x128 GEMM body.
// ---------------------------------------------------------------------------
__device__ __forceinline__ void gemm_body(
        const bf16_t* __restrict__ Asrc, const bf16_t* __restrict__ Bsrc,
        const float* __restrict__ bias, const float* __restrict__ resid,
        float* __restrict__ xout, bf16_t* __restrict__ bout,
        int mode, int m0, int n0)
{
    __shared__ bf16_t As[128 * 64];
    __shared__ bf16_t Bs[128 * 64];
    const int tid = threadIdx.x;
    const int w = tid >> 6, l = tid & 63;
    const int c = l & 15, g = l >> 4;
    const int wr = w >> 1, wc = w & 1;

    int srow[4], scol[4];
    uint32_t soff[4];
#pragma unroll
    for (int i = 0; i < 4; ++i) {
        int s = tid + i * 256;
        srow[i] = s >> 3;
        scol[i] = s & 7;
        soff[i] = (uint32_t)(s * 16) ^ (uint32_t)((srow[i] & 7) << 4);
    }

    bf16x8 areg[4], breg[4];
#pragma unroll
    for (int i = 0; i < 4; ++i) {
        areg[i] = *reinterpret_cast<const bf16x8*>(Asrc + (size_t)srow[i] * D_ + scol[i] * 8);
        breg[i] = *reinterpret_cast<const bf16x8*>(Bsrc + (size_t)srow[i] * D_ + scol[i] * 8);
    }

    f32x4 acc[4][4] = {};
    for (int kt = 0; kt < 16; ++kt) {
#pragma unroll
        for (int i = 0; i < 4; ++i) {
            *reinterpret_cast<bf16x8*>((char*)As + soff[i]) = areg[i];
            *reinterpret_cast<bf16x8*>((char*)Bs + soff[i]) = breg[i];
        }
        __syncthreads();
        if (kt + 1 < 16) {
            int k0 = (kt + 1) * 64;
#pragma unroll
            for (int i = 0; i < 4; ++i) {
                areg[i] = *reinterpret_cast<const bf16x8*>(Asrc + (size_t)srow[i] * D_ + k0 + scol[i] * 8);
                breg[i] = *reinterpret_cast<const bf16x8*>(Bsrc + (size_t)srow[i] * D_ + k0 + scol[i] * 8);
            }
        }
        bf16x8 bf0[4], bf1[4];
#pragma unroll
        for (int j = 0; j < 4; ++j) {
            int R = wc * 64 + j * 16 + c;
            const char* base = (const char*)Bs + R * 128;
            uint32_t msk = (uint32_t)((R & 7) << 4);
            bf0[j] = *reinterpret_cast<const bf16x8*>(base + ((g * 16) ^ msk));
            bf1[j] = *reinterpret_cast<const bf16x8*>(base + ((64 + g * 16) ^ msk));
        }
#pragma unroll
        for (int i = 0; i < 4; ++i) {
            int R = wr * 64 + i * 16 + c;
            const char* base = (const char*)As + R * 128;
            uint32_t msk = (uint32_t)((R & 7) << 4);
            bf16x8 a0 = *reinterpret_cast<const bf16x8*>(base + ((g * 16) ^ msk));
            bf16x8 a1 = *reinterpret_cast<const bf16x8*>(base + ((64 + g * 16) ^ msk));
#pragma unroll
            for (int j = 0; j < 4; ++j) {
                acc[i][j] = MFMA16(a0, bf0[j], acc[i][j]);
                acc[i][j] = MFMA16(a1, bf1[j], acc[i][j]);
            }
        }
        __syncthreads();
    }

#pragma unroll
    for (int i = 0; i < 4; ++i) {
#pragma unroll
        for (int j = 0; j < 4; ++j) {
#pragma unroll
            for (int r = 0; r < 4; ++r) {
                int P  = wr * 64 + i * 16 + g * 4 + r;
                int Qd = wc * 64 + j * 16 + c;
                float val = acc[i][j][r];
                if (mode == 2) {
                    int m = m0 + P, n = n0 + Qd;
                    xout[(size_t)m * D_ + n] = val + bias[n] + resid[(size_t)m * D_ + n];
                } else if (mode == 0) {
                    int m = m0 + P, n = n0 + Qd;
                    int bb = m >> 11, s = m & (S_ - 1);
                    int h = n >> 6, dk = n & 63;
                    bout[(((size_t)bb * H_ + h) * S_ + s) * DK_ + dk] = (bf16_t)(val + bias[n]);
                } else {
                    int n = n0 + P, m = m0 + Qd;
                    int bb = m >> 11, s = m & (S_ - 1);
                    int h = n >> 6, dk = n & 63;
                    bout[(((size_t)bb * H_ + h) * DK_ + dk) * S_ + s] = (bf16_t)(val + bias[n]);
                }
            }
        }
    }
}

__global__ __launch_bounds__(256) void qkv_gemm(
        const bf16_t* __restrict__ xq, const bf16_t* __restrict__ xk,
        const bf16_t* __restrict__ xv,
        const bf16_t* __restrict__ wq, const bf16_t* __restrict__ wk,
        const bf16_t* __restrict__ wv,
        const float* __restrict__ bq, const float* __restrict__ bk,
        const float* __restrict__ bv,
        bf16_t* __restrict__ qh, bf16_t* __restrict__ kh, bf16_t* __restrict__ vt)
{
    const int z = blockIdx.z;
    const int m0 = blockIdx.y * 128, n0 = blockIdx.x * 128;
    const bf16_t* X = (z == 0) ? xq : (z == 1) ? xk : xv;
    const bf16_t* W = (z == 0) ? wq : (z == 1) ? wk : wv;
    const float* bias = (z == 0) ? bq : (z == 1) ? bk : bv;
    bf16_t* out = (z == 0) ? qh : (z == 1) ? kh : vt;
    int mode = (z == 2) ? 1 : 0;
    const bf16_t* Asrc = (mode == 1) ? (W + (size_t)n0 * D_) : (X + (size_t)m0 * D_);
    const bf16_t* Bsrc = (mode == 1) ? (X + (size_t)m0 * D_) : (W + (size_t)n0 * D_);
    gemm_body(Asrc, Bsrc, bias, nullptr, nullptr, out, mode, m0, n0);
}

__global__ __launch_bounds__(256) void oproj_gemm(
        const bf16_t* __restrict__ ctx, const bf16_t* __restrict__ wo,
        const float* __restrict__ bo, const float* __restrict__ resid,
        float* __restrict__ x)
{
    const int m0 = blockIdx.y * 128, n0 = blockIdx.x * 128;
    gemm_body(ctx + (size_t)m0 * D_, wo + (size_t)n0 * D_, bo, resid, x, nullptr, 2, m0, n0);
}

// ---------------------------------------------------------------------------
// Fused attention. Pass 1: BK=128 (2 K-sub-tiles per barrier, 16 iters,
// 3 x 16 KB K buffers). Pass 2: r12 config exactly (3-deep K/V DMA, counted
// vmcnt, Pf fp32-LDS coalescing, NT stores). LDS: one flat 80 KB region,
// re-partitioned between passes.
// ---------------------------------------------------------------------------
__global__ __launch_bounds__(512) void fused_attn(
        const bf16_t* __restrict__ qh,   // [B,H,S,DK]
        const bf16_t* __restrict__ kh,   // [B,H,S,DK]
        const bf16_t* __restrict__ vt,   // [B,H,DK,S]
        const u16*    __restrict__ bits2,// [B*S*4][32] u16
        float* __restrict__ attn,        // [B,H,S,S]
        bf16_t* __restrict__ ctx)        // [B,S,D] bf16
{
    constexpr int TILE = 64;
    constexpr int NT = S_ / TILE;        // 32
    constexpr int NT2 = NT / 2;          // 16 (pass-1 BK=128 iterations)
    __shared__ __align__(16) char smem[81920];

    const int tid = threadIdx.x;
    const int w = tid >> 6, l = tid & 63;
    const int c = l & 15, g = l >> 4;

    const int id = blockIdx.x;
    const int xcd = id & 7, ixd = id >> 3;
    const int bh = xcd * 4 + (ixd >> 4);
    const int qt = ixd & 15;
    const int q0 = qt * 128 + w * 16;
    const int b = bh >> 4, h = bh & 15;

    const bf16_t* Q = qh + ((size_t)bh * S_ + q0) * DK_;
    const bf16_t* K = kh + (size_t)bh * S_ * DK_;
    const bf16_t* V = vt + (size_t)bh * DK_ * S_;
    float* Astrip = attn + ((size_t)bh * S_ + q0) * S_;

    u64 mreg[8];
    {
        const u64* mp = reinterpret_cast<const u64*>(
            bits2 + (((size_t)b * S_ + q0 + c) * 4 + g) * 32);
#pragma unroll
        for (int i = 0; i < 8; ++i) mreg[i] = mp[i];
    }

    bf16x8 qf0 = *reinterpret_cast<const bf16x8*>(&Q[c * DK_ + g * 8]);
    bf16x8 qf1 = *reinterpret_cast<const bf16x8*>(&Q[c * DK_ + 32 + g * 8]);

    const uint32_t rm = (uint32_t)((c & 7) << 4);   // K/V read XOR
    const uint32_t xr = (uint32_t)((c & 7) << 4);   // Pf row-c XOR

    //================= pass 1: row sums of exp (BK=128) =================
    {
        bf16_t* kband = (bf16_t*)smem;               // 3 x 8192 elems (16 KB)
        // staging: 1024 slots/tile; thread stages slot tid and tid+512
        const int r0 = tid >> 3;                     // rows 0..63
        const int cs = (tid & 7) ^ (r0 & 7);         // (r0+64)&7 == r0&7
        const bf16_t* Kg0 = K + (size_t)r0 * DK_ + cs * 8;
        const bf16_t* Kg1 = K + (size_t)(r0 + 64) * DK_ + cs * 8;
        const int o0 = __builtin_amdgcn_readfirstlane(w * 512);
        const int o1 = __builtin_amdgcn_readfirstlane(4096 + w * 512);

        gload16(Kg0, kband + o0);
        gload16(Kg1, kband + o1);
        gload16(Kg0 + (size_t)128 * DK_, kband + 8192 + o0);
        gload16(Kg1 + (size_t)128 * DK_, kband + 8192 + o1);
        asm volatile("s_waitcnt vmcnt(2)" ::: "memory");
        __builtin_amdgcn_s_barrier();

        float l_r = 0.f;
        int bc = 0;
        for (int t = 0; t < NT2; ++t) {
            if (t + 2 < NT2) {
                int b2 = bc + 2; if (b2 >= 3) b2 -= 3;
                gload16(Kg0 + (size_t)(t + 2) * 128 * DK_, kband + b2 * 8192 + o0);
                gload16(Kg1 + (size_t)(t + 2) * 128 * DK_, kband + b2 * 8192 + o1);
            }
            __builtin_amdgcn_sched_barrier(0);
            const char* kb = (const char*)(kband + bc * 8192);
            float ps = 0.f;
#pragma unroll
            for (int half = 0; half < 2; ++half) {
                int tt = t * 2 + half;
                u16 m16 = (u16)(mreg[tt >> 2] >> ((tt & 3) << 4));
                f32x4 acc[4] = {};
                __builtin_amdgcn_s_setprio(1);
#pragma unroll
                for (int tk = 0; tk < 4; ++tk) {
                    uint32_t base = (uint32_t)(half * 8192 + (tk * 16 + c) * 128 + g * 16);
                    bf16x8 a0 = *reinterpret_cast<const bf16x8*>(kb + (base ^ rm));
                    bf16x8 a1 = *reinterpret_cast<const bf16x8*>(kb + ((base + 64) ^ rm));
                    acc[tk] = MFMA16(a0, qf0, acc[tk]);
                    acc[tk] = MFMA16(a1, qf1, acc[tk]);
                }
                __builtin_amdgcn_s_setprio(0);
#pragma unroll
                for (int tk = 0; tk < 4; ++tk) {
#pragma unroll
                    for (int r = 0; r < 4; ++r) {
                        float e = __expf(acc[tk][r] * 0.125f);
                        e = ((m16 >> (tk * 4 + r)) & 1) ? e : 0.f;
                        ps += e;
                    }
                }
            }
            l_r += ps;
            if (t + 2 < NT2) asm volatile("s_waitcnt vmcnt(2)" ::: "memory");
            else             asm volatile("s_waitcnt vmcnt(0)" ::: "memory");
            asm volatile("s_waitcnt lgkmcnt(0)" ::: "memory");
            __builtin_amdgcn_sched_barrier(0);
            __builtin_amdgcn_s_barrier();
            bc = (bc == 2) ? 0 : bc + 1;
        }
        l_r += __shfl_xor(l_r, 16);
        l_r += __shfl_xor(l_r, 32);
        // stash inv_l in a register across the LDS repartition
        smem[0] = smem[0];  // no-op to keep smem live
        // fallthrough with inv_l
        float inv_l = 1.0f / l_r;

        //================= pass 2: emit P + PV =================
        bf16_t* Kbuf = (bf16_t*)smem;                    // 3 x 4096 elems
        bf16_t* Vbuf = (bf16_t*)(smem + 24576);          // 3 x 4096 elems
        float*  Pfb  = (float*)(smem + 49152);           // 8 x 1024 floats

        const int row_s = (w << 3) + (l >> 3);
        const int csx = (l & 7) ^ (row_s & 7);
        const bf16_t* Kg = K + (size_t)row_s * DK_ + csx * 8;
        const bf16_t* Vg = V + (size_t)row_s * S_ + csx * 8;
        const int woffu = __builtin_amdgcn_readfirstlane(w * 512);

        gload16(Kg, Kbuf + woffu);
        gload16(Vg, Vbuf + woffu);
        gload16(Kg + (size_t)TILE * DK_, Kbuf + 4096 + woffu);
        gload16(Vg + TILE, Vbuf + 4096 + woffu);
        asm volatile("s_waitcnt vmcnt(2)" ::: "memory");
        __builtin_amdgcn_s_barrier();

        float* pf = Pfb + w * 1024;
        f32x4 oacc[4] = {};
        bc = 0;
        for (int t = 0; t < NT; ++t) {
            if (t + 2 < NT) {
                int b2 = bc + 2; if (b2 >= 3) b2 -= 3;
                gload16(Kg + (size_t)(t + 2) * TILE * DK_, Kbuf + b2 * 4096 + woffu);
                gload16(Vg + (t + 2) * TILE, Vbuf + b2 * 4096 + woffu);
            }
            __builtin_amdgcn_sched_barrier(0);
            u16 m16 = (u16)(mreg[t >> 2] >> ((t & 3) << 4));
            const char* kb2 = (const char*)(Kbuf + bc * 4096);
            const char* vb = (const char*)(Vbuf + bc * 4096);
            f32x4 acc[4] = {};
            __builtin_amdgcn_s_setprio(1);
#pragma unroll
            for (int tk = 0; tk < 4; ++tk) {
                uint32_t base = (uint32_t)((tk * 16 + c) * 128 + g * 16);
                bf16x8 a0 = *reinterpret_cast<const bf16x8*>(kb2 + (base ^ rm));
                bf16x8 a1 = *reinterpret_cast<const bf16x8*>(kb2 + ((base + 64) ^ rm));
                acc[tk] = MFMA16(a0, qf0, acc[tk]);
                acc[tk] = MFMA16(a1, qf1, acc[tk]);
            }
            __builtin_amdgcn_s_setprio(0);
#pragma unroll
            for (int tk = 0; tk < 4; ++tk) {
                f32x4 pv;
#pragma unroll
                for (int r = 0; r < 4; ++r) {
                    float p = __expf(acc[tk][r] * 0.125f) * inv_l;
                    pv[r] = ((m16 >> (tk * 4 + r)) & 1) ? p : 0.f;
                }
                *reinterpret_cast<f32x4*>((char*)pf + ((uint32_t)(c * 256 + tk * 64 + g * 16) ^ xr)) = pv;
            }
            asm volatile("s_waitcnt lgkmcnt(0)" ::: "memory");
            __builtin_amdgcn_sched_barrier(0);
#pragma unroll
            for (int i = 0; i < 4; ++i) {
                int row = i * 4 + (l >> 4);
                uint32_t off = (uint32_t)(i * 1024 + l * 16) ^ (uint32_t)((row & 7) << 4);
                f32x4 sv = *reinterpret_cast<const f32x4*>((char*)pf + off);
                __builtin_nontemporal_store(sv,
                    reinterpret_cast<f32x4*>(Astrip + (size_t)row * S_ + t * TILE + (l & 15) * 4));
            }
            f32x4 p0a = *reinterpret_cast<const f32x4*>((char*)pf + ((uint32_t)(c * 256 + g * 32) ^ xr));
            f32x4 p0b = *reinterpret_cast<const f32x4*>((char*)pf + ((uint32_t)(c * 256 + g * 32 + 16) ^ xr));
            f32x4 p1a = *reinterpret_cast<const f32x4*>((char*)pf + ((uint32_t)(c * 256 + 128 + g * 32) ^ xr));
            f32x4 p1b = *reinterpret_cast<const f32x4*>((char*)pf + ((uint32_t)(c * 256 + 128 + g * 32 + 16) ^ xr));
            bf16x8 pa0 = { (bf16_t)p0a[0], (bf16_t)p0a[1], (bf16_t)p0a[2], (bf16_t)p0a[3],
                           (bf16_t)p0b[0], (bf16_t)p0b[1], (bf16_t)p0b[2], (bf16_t)p0b[3] };
            bf16x8 pa1 = { (bf16_t)p1a[0], (bf16_t)p1a[1], (bf16_t)p1a[2], (bf16_t)p1a[3],
                           (bf16_t)p1b[0], (bf16_t)p1b[1], (bf16_t)p1b[2], (bf16_t)p1b[3] };
            __builtin_amdgcn_s_setprio(1);
#pragma unroll
            for (int tk = 0; tk < 4; ++tk) {
                uint32_t base = (uint32_t)((tk * 16 + c) * 128 + g * 16);
                bf16x8 b0 = *reinterpret_cast<const bf16x8*>(vb + (base ^ rm));
                bf16x8 b1 = *reinterpret_cast<const bf16x8*>(vb + ((base + 64) ^ rm));
                oacc[tk] = MFMA16(pa0, b0, oacc[tk]);
                oacc[tk] = MFMA16(pa1, b1, oacc[tk]);
            }
            __builtin_amdgcn_s_setprio(0);
            if (t + 2 < NT)       asm volatile("s_waitcnt vmcnt(6)" ::: "memory");
            else if (t + 1 < NT)  asm volatile("s_waitcnt vmcnt(4)" ::: "memory");
            asm volatile("s_waitcnt lgkmcnt(0)" ::: "memory");
            __builtin_amdgcn_sched_barrier(0);
            __builtin_amdgcn_s_barrier();
            bc = (bc == 2) ? 0 : bc + 1;
        }

#pragma unroll
        for (int tk = 0; tk < 4; ++tk) {
#pragma unroll
            for (int r = 0; r < 4; ++r) {
                int qrow = q0 + g * 4 + r;
                ctx[((size_t)b * S_ + qrow) * D_ + h * DK_ + tk * 16 + c] = (bf16_t)oacc[tk][r];
            }
        }
    }
}

// ---------------------------------------------------------------------------
// LayerNorm over last dim (1024), 4096 rows
// ---------------------------------------------------------------------------
__global__ void ln_kernel(const float* __restrict__ x, const float* __restrict__ gamma,
                          const float* __restrict__ beta, float* __restrict__ out)
{
    int row = blockIdx.x;
    const float* xr = x + (size_t)row * D_;
    int tid = threadIdx.x;
    float v[4];
    float s = 0.f;
#pragma unroll
    for (int i = 0; i < 4; ++i) {
        v[i] = xr[tid + i * 256];
        s += v[i];
    }
#pragma unroll
    for (int off = 32; off > 0; off >>= 1) s += __shfl_xor(s, off);
    __shared__ float red[4];
    int wid = tid >> 6, lane = tid & 63;
    if (lane == 0) red[wid] = s;
    __syncthreads();
    float mu = (red[0] + red[1] + red[2] + red[3]) * (1.0f / D_);
    float vs = 0.f;
#pragma unroll
    for (int i = 0; i < 4; ++i) {
        float d = v[i] - mu;
        vs += d * d;
    }
#pragma unroll
    for (int off = 32; off > 0; off >>= 1) vs += __shfl_xor(vs, off);
    __syncthreads();
    __shared__ float red2[4];
    if (lane == 0) red2[wid] = vs;
    __syncthreads();
    float var = (red2[0] + red2[1] + red2[2] + red2[3]) * (1.0f / D_);
    float rs = rsqrtf(var + EPS_);
#pragma unroll
    for (int i = 0; i < 4; ++i) {
        int c = tid + i * 256;
        out[(size_t)row * D_ + c] = (v[i] - mu) * rs * gamma[c] + beta[c];
    }
}

extern "C" void kernel_launch(void* const* d_in, const int* in_sizes, int n_in,
                              void* d_out, int out_size, void* d_ws, size_t ws_size,
                              hipStream_t stream) {
    const float* q    = (const float*)d_in[0];
    const float* k    = (const float*)d_in[1];
    const float* v    = (const float*)d_in[2];
    const int*   mask = (const int*)d_in[3];
    const float* Wq   = (const float*)d_in[4];
    const float* bq   = (const float*)d_in[5];
    const float* Wk   = (const float*)d_in[6];
    const float* bk   = (const float*)d_in[7];
    const float* Wv   = (const float*)d_in[8];
    const float* bv   = (const float*)d_in[9];
    const float* Wo   = (const float*)d_in[10];
    const float* bo   = (const float*)d_in[11];
    const float* gamma= (const float*)d_in[12];
    const float* beta = (const float*)d_in[13];

    float* out  = (float*)d_out;                       // [B,S,D]
    float* attn = out + (size_t)B_ * S_ * D_;          // [B,H,S,S]

    uint8_t* ws = (uint8_t*)d_ws;
    bf16_t* xq  = (bf16_t*)(ws);
    bf16_t* xk  = (bf16_t*)(ws + ((size_t)8  << 20));
    bf16_t* xv  = (bf16_t*)(ws + ((size_t)16 << 20));
    bf16_t* wqb = (bf16_t*)(ws + ((size_t)24 << 20));
    bf16_t* wkb = (bf16_t*)(ws + ((size_t)26 << 20));
    bf16_t* wvb = (bf16_t*)(ws + ((size_t)28 << 20));
    bf16_t* wob = (bf16_t*)(ws + ((size_t)30 << 20));
    bf16_t* qh  = (bf16_t*)(ws + ((size_t)32 << 20));
    u16*    bits= (u16*)   (ws + ((size_t)40 << 20));  // 1 MB
    bf16_t* kh  = (bf16_t*)(ws + ((size_t)42 << 20));
    bf16_t* vt  = (bf16_t*)(ws + ((size_t)50 << 20));
    bf16_t* ctx = (bf16_t*)(ws);                       // over xq (dead)
    float*  x   = (float*) (ws + ((size_t)8 << 20));   // over xk+xv (dead)

    dim3 blk(256);
    prep<<<dim3(40960), blk, 0, stream>>>(mask, bits, q, k, v, xq, xk, xv,
                                          Wq, Wk, Wv, Wo, wqb, wkb, wvb, wob);

    dim3 gqkv(D_ / 128, (B_ * S_) / 128, 3);           // (8, 32, 3)
    qkv_gemm<<<gqkv, blk, 0, stream>>>(xq, xk, xv, wqb, wkb, wvb,
                                       bq, bk, bv, qh, kh, vt);

    fused_attn<<<dim3(512), dim3(512), 0, stream>>>(qh, kh, vt, bits, attn, ctx);

    dim3 ggemm(D_ / 128, (B_ * S_) / 128);             // (8, 32)
    oproj_gemm<<<ggemm, blk, 0, stream>>>(ctx, wob, bo, q, x);
    ln_kernel<<<dim3(B_ * S_), blk, 0, stream>>>(x, gamma, beta, out);
}